// Round 1
// baseline (153.426 us; speedup 1.0000x reference)
//
#include <hip/hip_runtime.h>
#include <hip/hip_bf16.h>
#include <stdint.h>

typedef __bf16 bf16;
typedef __attribute__((ext_vector_type(8))) __bf16 bf16x8;
typedef __attribute__((ext_vector_type(4))) float f32x4;

#define B_DIM 128
#define F_DIM 256
#define C_DIM 512
#define HID   2048
#define F2    (F_DIM/2)      // 128
#define C2    (C_DIM/2)      // 256
#define MROWS (B_DIM*F2)     // 16384

// ---- workspace layout (bytes) ----
// [OFF_W1,  +2MB)   : fc1_w bf16 [2048][512]
// [OFF_W2,  +1MB)   : fc2_w bf16 [256][2048]
// [OFF_LLUP,+16MB)  : ll_up bf16 [16384][512]  (later reused as ll_new f32 [16384][256])
// [OFF_H,   +64MB)  : H bf16 [16384][2048]
// total ≈ 83 MB
static constexpr size_t OFF_W1   = 0;
static constexpr size_t OFF_W2   = OFF_W1 + (size_t)HID * C_DIM * 2;   // 2,097,152
static constexpr size_t OFF_LLUP = OFF_W2 + (size_t)C2 * HID * 2;      // 3,145,728
static constexpr size_t OFF_H    = OFF_LLUP + (size_t)MROWS * C_DIM * 2; // 19,922,944

__device__ __forceinline__ unsigned short bfbits(float f) {
    bf16 h = (bf16)f;
    return __builtin_bit_cast(unsigned short, h);
}

// async global->LDS, 16B per lane. LDS dest must be linear in lane order.
typedef const __attribute__((address_space(1))) unsigned int as1_uint;
typedef __attribute__((address_space(3))) unsigned int as3_uint;
__device__ __forceinline__ void gld_lds16(const void* g, void* l) {
    as1_uint* gp = (as1_uint*)(uintptr_t)g;
    as3_uint* lp = (as3_uint*)(uintptr_t)l;
    __builtin_amdgcn_global_load_lds(gp, lp, 16, 0, 0);
}

// ---------------- K0: weight f32 -> bf16 ----------------
__global__ __launch_bounds__(256) void cvt_weights(
    const float* __restrict__ w1, const float* __restrict__ w2,
    ushort* __restrict__ o1, ushort* __restrict__ o2)
{
    const int n1 = HID * C_DIM / 4;  // 262144 float4
    const int n2 = C2 * HID / 4;     // 131072 float4
    int idx = blockIdx.x * 256 + threadIdx.x;
    if (idx < n1) {
        float4 v = ((const float4*)w1)[idx];
        ushort4 u;
        u.x = bfbits(v.x); u.y = bfbits(v.y); u.z = bfbits(v.z); u.w = bfbits(v.w);
        ((ushort4*)o1)[idx] = u;
    } else if (idx < n1 + n2) {
        int j = idx - n1;
        float4 v = ((const float4*)w2)[j];
        ushort4 u;
        u.x = bfbits(v.x); u.y = bfbits(v.y); u.z = bfbits(v.z); u.w = bfbits(v.w);
        ((ushort4*)o2)[j] = u;
    }
}

// ---------------- K1: DWT(ll) + linear interp 256->512, bf16 out ----------------
// one block per (b, f2) row pair; 256 threads
__global__ __launch_bounds__(256) void dwt_interp_kernel(
    const float* __restrict__ x, bf16* __restrict__ llup)
{
    const int bf = blockIdx.x;                    // b*128 + f2
    const float* r0 = x + (size_t)(bf >> 7) * F_DIM * C_DIM
                        + (size_t)((bf & 127) * 2) * C_DIM;
    const float* r1 = r0 + C_DIM;
    __shared__ float ll[C2];
    const int t = threadIdx.x;                    // 0..255
    float2 p0 = ((const float2*)r0)[t];
    float2 p1 = ((const float2*)r1)[t];
    ll[t] = 0.5f * (p0.x + p0.y + p1.x + p1.y);
    __syncthreads();
    bf16* orow = llup + (size_t)bf * C_DIM;
#pragma unroll
    for (int jj = 0; jj < 2; ++jj) {
        int j = t + jj * 256;
        float pos = (float)j * (255.0f / 511.0f);
        int i0 = (int)pos;                        // floor (pos>=0)
        if (i0 > 254) i0 = 254;
        float w = pos - (float)i0;
        float v = ll[i0] * (1.0f - w) + ll[i0 + 1] * w;
        orow[j] = (bf16)v;
    }
}

// ---------------- GEMM: C[M,N] = A[M,K] * B[N,K]^T (+bias, optional GELU) ----------------
// m97 structure: 128x128 tile, BK=32, 256 threads = 4 waves (2x2), each wave 64x64 out.
// EPI==1: bf16 out with exact GELU;  EPI==0: f32 out, bias only.
template <int EPI>
__global__ __launch_bounds__(256) void gemm_bt(
    const bf16* __restrict__ A, const bf16* __restrict__ Bw,
    const float* __restrict__ bias, void* __restrict__ Cout,
    int M, int N, int K)
{
    __shared__ bf16 As[128][32];
    __shared__ bf16 Bs[128][32];
    const int tid = threadIdx.x;
    const int l = tid & 63;
    const int w = tid >> 6;
    const int wr = w >> 1, wc = w & 1;
    const int row0 = blockIdx.y * 128;
    const int col0 = blockIdx.x * 128;

    f32x4 acc[4][4];
#pragma unroll
    for (int m = 0; m < 4; ++m)
#pragma unroll
        for (int n = 0; n < 4; ++n)
            acc[m][n] = (f32x4){0.f, 0.f, 0.f, 0.f};

    const int lk = (l >> 4) << 3;  // k offset: lane-group * 8 (same map for A and B)
    const int lr = l & 15;

    for (int k0 = 0; k0 < K; k0 += 32) {
#pragma unroll
        for (int i = 0; i < 2; ++i) {
            int c = i * 256 + tid;       // 16B chunk index, 512 chunks per tile
            int r = c >> 2;
            int cc = (c & 3) << 3;
            gld_lds16(A  + (size_t)(row0 + r) * K + k0 + cc, (bf16*)&As[0][0] + (size_t)c * 8);
            gld_lds16(Bw + (size_t)(col0 + r) * K + k0 + cc, (bf16*)&Bs[0][0] + (size_t)c * 8);
        }
        __syncthreads();
        bf16x8 af[4], bf_[4];
#pragma unroll
        for (int m = 0; m < 4; ++m)
            af[m] = *(const bf16x8*)&As[wr * 64 + m * 16 + lr][lk];
#pragma unroll
        for (int n = 0; n < 4; ++n)
            bf_[n] = *(const bf16x8*)&Bs[wc * 64 + n * 16 + lr][lk];
#pragma unroll
        for (int m = 0; m < 4; ++m)
#pragma unroll
            for (int n = 0; n < 4; ++n)
                acc[m][n] = __builtin_amdgcn_mfma_f32_16x16x32_bf16(af[m], bf_[n], acc[m][n], 0, 0, 0);
        __syncthreads();
    }

    // epilogue: C/D layout col=lane&15, row=(lane>>4)*4+reg  [verified m89/m91]
    const int rbase = row0 + wr * 64 + ((l >> 4) << 2);
    const int cbase = col0 + wc * 64 + (l & 15);
#pragma unroll
    for (int m = 0; m < 4; ++m) {
#pragma unroll
        for (int n = 0; n < 4; ++n) {
            const int col = cbase + n * 16;
            const float bs = bias[col];
            const int row = rbase + m * 16;
#pragma unroll
            for (int j = 0; j < 4; ++j) {
                float v = acc[m][n][j] + bs;
                if (EPI == 1) {
                    float g = 0.5f * v * (1.0f + erff(v * 0.70710678118654752f));
                    ((bf16*)Cout)[(size_t)(row + j) * N + col] = (bf16)g;
                } else {
                    ((float*)Cout)[(size_t)(row + j) * N + col] = v;
                }
            }
        }
    }
}

// ---------------- K4: inverse DWT, recomputing lh/hl/hh from x ----------------
__global__ __launch_bounds__(256) void idwt_kernel(
    const float* __restrict__ x, const float* __restrict__ lln, float* __restrict__ out)
{
    int t = blockIdx.x * 256 + threadIdx.x;       // 0 .. 128*128*256-1
    int c2 = t & 255;
    int f2 = (t >> 8) & 127;
    int b  = t >> 15;
    const float* xr0 = x + ((size_t)b * F_DIM + 2 * f2) * C_DIM;
    const float* xr1 = xr0 + C_DIM;
    float2 p0 = ((const float2*)xr0)[c2];
    float2 p1 = ((const float2*)xr1)[c2];
    float a = p0.x, bb = p0.y, c = p1.x, d = p1.y;
    float ll = lln[((size_t)b * F2 + f2) * C2 + c2];
    float lh = 0.5f * (a + bb - c - d);
    float hl = 0.5f * (a - bb + c - d);
    float hh = 0.5f * (a - bb - c + d);
    float2 o0, o1;
    o0.x = 0.5f * (ll + lh + hl + hh);
    o0.y = 0.5f * (ll + lh - hl - hh);
    o1.x = 0.5f * (ll - lh + hl - hh);
    o1.y = 0.5f * (ll - lh - hl + hh);
    float* or0 = out + ((size_t)b * F_DIM + 2 * f2) * C_DIM;
    ((float2*)or0)[c2] = o0;
    ((float2*)(or0 + C_DIM))[c2] = o1;
}

extern "C" void kernel_launch(void* const* d_in, const int* in_sizes, int n_in,
                              void* d_out, int out_size, void* d_ws, size_t ws_size,
                              hipStream_t stream) {
    const float* x     = (const float*)d_in[0];
    const float* fc1_w = (const float*)d_in[1];
    const float* fc1_b = (const float*)d_in[2];
    const float* fc2_w = (const float*)d_in[3];
    const float* fc2_b = (const float*)d_in[4];
    float* out = (float*)d_out;

    char* ws = (char*)d_ws;
    bf16*  w1b   = (bf16*)(ws + OFF_W1);
    bf16*  w2b   = (bf16*)(ws + OFF_W2);
    bf16*  llup  = (bf16*)(ws + OFF_LLUP);
    float* llnew = (float*)(ws + OFF_LLUP);   // reuses llup region (same byte size)
    bf16*  H     = (bf16*)(ws + OFF_H);

    cvt_weights<<<1536, 256, 0, stream>>>(fc1_w, fc2_w, (ushort*)w1b, (ushort*)w2b);
    dwt_interp_kernel<<<B_DIM * F2, 256, 0, stream>>>(x, llup);
    gemm_bt<1><<<dim3(HID / 128, MROWS / 128), 256, 0, stream>>>(llup, w1b, fc1_b, H, MROWS, HID, C_DIM);
    gemm_bt<0><<<dim3(C2 / 128, MROWS / 128), 256, 0, stream>>>(H, w2b, fc2_b, llnew, MROWS, C2, HID);
    idwt_kernel<<<B_DIM * F2 * C2 / 256, 256, 0, stream>>>(x, llnew, out);
}

// Round 2
// 123.558 us; speedup vs baseline: 1.2417x; 1.2417x over previous
//
#include <hip/hip_runtime.h>
#include <hip/hip_bf16.h>
#include <stdint.h>

typedef __bf16 bf16;
typedef __attribute__((ext_vector_type(8))) __bf16 bf16x8;
typedef __attribute__((ext_vector_type(4))) float f32x4;

#define B_DIM 128
#define F_DIM 256
#define C_DIM 512
#define HID   2048
#define F2    (F_DIM/2)      // 128
#define C2    (C_DIM/2)      // 256
#define MROWS (B_DIM*F2)     // 16384

// ---- workspace layout (bytes) ----
// [OFF_W1P, +1MB)  : W1' bf16 [2048][256]   (interp folded into fc1_w)
// [OFF_W2,  +1MB)  : fc2_w bf16 [256][2048]
// [OFF_LL,  +8.4MB): ll bf16 [16384][256]
// [OFF_H,   +64MB) : H bf16 [16384][2048]
static constexpr size_t OFF_W1P = 0;
static constexpr size_t OFF_W2  = OFF_W1P + (size_t)HID * C2 * 2;      // 1,048,576
static constexpr size_t OFF_LL  = OFF_W2  + (size_t)C2 * HID * 2;      // 2,097,152
static constexpr size_t OFF_H   = OFF_LL  + (size_t)MROWS * C2 * 2;    // 10,485,760

__device__ __forceinline__ unsigned short bfbits(float f) {
    bf16 h = (bf16)f;
    return __builtin_bit_cast(unsigned short, h);
}

// async global->LDS, 16B per lane. LDS dest must be linear in lane order.
typedef const __attribute__((address_space(1))) unsigned int as1_uint;
typedef __attribute__((address_space(3))) unsigned int as3_uint;
__device__ __forceinline__ void gld_lds16(const void* g, void* l) {
    as1_uint* gp = (as1_uint*)(uintptr_t)g;
    as3_uint* lp = (as3_uint*)(uintptr_t)l;
    __builtin_amdgcn_global_load_lds(gp, lp, 16, 0, 0);
}

// ---------------- K0: prep — fold interp into W1, cvt W2, DWT(ll) ----------------
// blocks [0,2048)        : W1'[h][i] = sum_j coef(j->i) * fc1_w[h][j]   (bf16 out)
// blocks [2048,2560)     : fc2_w f32 -> bf16
// blocks [2560,2560+16384): ll[bf][c2] = 0.5*(a+b+c+d)                  (bf16 out)
__global__ __launch_bounds__(256) void prep_kernel(
    const float* __restrict__ w1, const float* __restrict__ w2,
    const float* __restrict__ x,
    ushort* __restrict__ w1p, ushort* __restrict__ w2b, bf16* __restrict__ ll)
{
    const int blk = blockIdx.x;
    const int t = threadIdx.x;
    if (blk < 2048) {
        // one thread per (h, i)
        int idx = blk * 256 + t;
        int h = idx >> 8, i = idx & 255;
        const float* wrow = w1 + (size_t)h * C_DIM;
        float acc = 0.f;
        int jlo = (i == 0) ? 0 : (int)((float)(i - 1) * (511.0f / 255.0f));
        int jhi = (int)((float)(i + 1) * (511.0f / 255.0f)) + 1;
        if (jhi > 511) jhi = 511;
        for (int j = jlo; j <= jhi; ++j) {
            float pos = (float)j * (255.0f / 511.0f);
            int i0 = (int)pos;
            if (i0 > 254) i0 = 254;
            float w = pos - (float)i0;
            float coef = (i0 == i) ? (1.0f - w) : ((i0 + 1 == i) ? w : 0.0f);
            acc += coef * wrow[j];
        }
        w1p[(size_t)h * C2 + i] = bfbits(acc);
    } else if (blk < 2560) {
        int idx = (blk - 2048) * 256 + t;      // 0..131071 float4s
        float4 v = ((const float4*)w2)[idx];
        ushort4 u;
        u.x = bfbits(v.x); u.y = bfbits(v.y); u.z = bfbits(v.z); u.w = bfbits(v.w);
        ((ushort4*)w2b)[idx] = u;
    } else {
        int bf = blk - 2560;                   // 0..16383
        const float* r0 = x + (size_t)(bf >> 7) * F_DIM * C_DIM
                            + (size_t)((bf & 127) * 2) * C_DIM;
        float2 p0 = ((const float2*)r0)[t];
        float2 p1 = ((const float2*)(r0 + C_DIM))[t];
        ll[(size_t)bf * C2 + t] = (bf16)(0.5f * (p0.x + p0.y + p1.x + p1.y));
    }
}

// ---------------- GEMM1: H = GELU(ll * W1'^T + b1), bf16 out ----------------
// m97 structure: 128x128 tile, BK=32, 256 threads = 4 waves (2x2), each wave 64x64 out.
__global__ __launch_bounds__(256) void gemm1_kernel(
    const bf16* __restrict__ A, const bf16* __restrict__ Bw,
    const float* __restrict__ bias, bf16* __restrict__ Cout,
    int M, int N, int K)
{
    __shared__ bf16 As[128][32];
    __shared__ bf16 Bs[128][32];
    const int tid = threadIdx.x;
    const int l = tid & 63;
    const int w = tid >> 6;
    const int wr = w >> 1, wc = w & 1;
    const int row0 = blockIdx.y * 128;
    const int col0 = blockIdx.x * 128;

    f32x4 acc[4][4];
#pragma unroll
    for (int m = 0; m < 4; ++m)
#pragma unroll
        for (int n = 0; n < 4; ++n)
            acc[m][n] = (f32x4){0.f, 0.f, 0.f, 0.f};

    const int lk = (l >> 4) << 3;
    const int lr = l & 15;

    for (int k0 = 0; k0 < K; k0 += 32) {
#pragma unroll
        for (int i = 0; i < 2; ++i) {
            int c = i * 256 + tid;
            int r = c >> 2;
            int cc = (c & 3) << 3;
            gld_lds16(A  + (size_t)(row0 + r) * K + k0 + cc, (bf16*)&As[0][0] + (size_t)c * 8);
            gld_lds16(Bw + (size_t)(col0 + r) * K + k0 + cc, (bf16*)&Bs[0][0] + (size_t)c * 8);
        }
        __syncthreads();
        bf16x8 af[4], bf_[4];
#pragma unroll
        for (int m = 0; m < 4; ++m)
            af[m] = *(const bf16x8*)&As[wr * 64 + m * 16 + lr][lk];
#pragma unroll
        for (int n = 0; n < 4; ++n)
            bf_[n] = *(const bf16x8*)&Bs[wc * 64 + n * 16 + lr][lk];
#pragma unroll
        for (int m = 0; m < 4; ++m)
#pragma unroll
            for (int n = 0; n < 4; ++n)
                acc[m][n] = __builtin_amdgcn_mfma_f32_16x16x32_bf16(af[m], bf_[n], acc[m][n], 0, 0, 0);
        __syncthreads();
    }

    const int rbase = row0 + wr * 64 + ((l >> 4) << 2);
    const int cbase = col0 + wc * 64 + (l & 15);
#pragma unroll
    for (int m = 0; m < 4; ++m) {
#pragma unroll
        for (int n = 0; n < 4; ++n) {
            const int col = cbase + n * 16;
            const float bs = bias[col];
            const int row = rbase + m * 16;
#pragma unroll
            for (int j = 0; j < 4; ++j) {
                float v = acc[m][n][j] + bs;
                float g = 0.5f * v * (1.0f + erff(v * 0.70710678118654752f));
                Cout[(size_t)(row + j) * N + col] = (bf16)g;
            }
        }
    }
}

// ---------------- GEMM2 + fused inverse DWT ----------------
// C[row=bf][col=c2] = H[bf,:] . W2[c2,:] + b2   -> ll_new, then idwt with
// lh/hl/hh recomputed from x, writing the 2x2 output block directly.
__global__ __launch_bounds__(256) void gemm2_idwt_kernel(
    const bf16* __restrict__ A, const bf16* __restrict__ Bw,
    const float* __restrict__ bias, const float* __restrict__ x,
    float* __restrict__ out, int M, int N, int K)
{
    __shared__ bf16 As[128][32];
    __shared__ bf16 Bs[128][32];
    const int tid = threadIdx.x;
    const int l = tid & 63;
    const int w = tid >> 6;
    const int wr = w >> 1, wc = w & 1;
    const int row0 = blockIdx.y * 128;
    const int col0 = blockIdx.x * 128;

    f32x4 acc[4][4];
#pragma unroll
    for (int m = 0; m < 4; ++m)
#pragma unroll
        for (int n = 0; n < 4; ++n)
            acc[m][n] = (f32x4){0.f, 0.f, 0.f, 0.f};

    const int lk = (l >> 4) << 3;
    const int lr = l & 15;

    for (int k0 = 0; k0 < K; k0 += 32) {
#pragma unroll
        for (int i = 0; i < 2; ++i) {
            int c = i * 256 + tid;
            int r = c >> 2;
            int cc = (c & 3) << 3;
            gld_lds16(A  + (size_t)(row0 + r) * K + k0 + cc, (bf16*)&As[0][0] + (size_t)c * 8);
            gld_lds16(Bw + (size_t)(col0 + r) * K + k0 + cc, (bf16*)&Bs[0][0] + (size_t)c * 8);
        }
        __syncthreads();
        bf16x8 af[4], bf_[4];
#pragma unroll
        for (int m = 0; m < 4; ++m)
            af[m] = *(const bf16x8*)&As[wr * 64 + m * 16 + lr][lk];
#pragma unroll
        for (int n = 0; n < 4; ++n)
            bf_[n] = *(const bf16x8*)&Bs[wc * 64 + n * 16 + lr][lk];
#pragma unroll
        for (int m = 0; m < 4; ++m)
#pragma unroll
            for (int n = 0; n < 4; ++n)
                acc[m][n] = __builtin_amdgcn_mfma_f32_16x16x32_bf16(af[m], bf_[n], acc[m][n], 0, 0, 0);
        __syncthreads();
    }

    const int rbase = row0 + wr * 64 + ((l >> 4) << 2);
    const int cbase = col0 + wc * 64 + (l & 15);
#pragma unroll
    for (int m = 0; m < 4; ++m) {
#pragma unroll
        for (int n = 0; n < 4; ++n) {
            const int col = cbase + n * 16;     // c2
            const float bs = bias[col];
#pragma unroll
            for (int j = 0; j < 4; ++j) {
                const int row = rbase + m * 16 + j;   // bf = b*128 + f2
                const int b  = row >> 7;
                const int f2 = row & 127;
                const float* xr0 = x + ((size_t)b * F_DIM + 2 * f2) * C_DIM;
                float2 p0 = ((const float2*)xr0)[col];
                float2 p1 = ((const float2*)(xr0 + C_DIM))[col];
                float a = p0.x, bb = p0.y, c = p1.x, d = p1.y;
                float llv = acc[m][n][j] + bs;
                float lh = 0.5f * (a + bb - c - d);
                float hl = 0.5f * (a - bb + c - d);
                float hh = 0.5f * (a - bb - c + d);
                float2 o0, o1;
                o0.x = 0.5f * (llv + lh + hl + hh);
                o0.y = 0.5f * (llv + lh - hl - hh);
                o1.x = 0.5f * (llv - lh + hl - hh);
                o1.y = 0.5f * (llv - lh - hl + hh);
                float* or0 = out + ((size_t)b * F_DIM + 2 * f2) * C_DIM;
                ((float2*)or0)[col] = o0;
                ((float2*)(or0 + C_DIM))[col] = o1;
            }
        }
    }
}

extern "C" void kernel_launch(void* const* d_in, const int* in_sizes, int n_in,
                              void* d_out, int out_size, void* d_ws, size_t ws_size,
                              hipStream_t stream) {
    const float* x     = (const float*)d_in[0];
    const float* fc1_w = (const float*)d_in[1];
    const float* fc1_b = (const float*)d_in[2];
    const float* fc2_w = (const float*)d_in[3];
    const float* fc2_b = (const float*)d_in[4];
    float* out = (float*)d_out;

    char* ws = (char*)d_ws;
    bf16* w1p = (bf16*)(ws + OFF_W1P);
    bf16* w2b = (bf16*)(ws + OFF_W2);
    bf16* ll  = (bf16*)(ws + OFF_LL);
    bf16* H   = (bf16*)(ws + OFF_H);

    prep_kernel<<<2560 + MROWS, 256, 0, stream>>>(fc1_w, fc2_w, x,
                                                  (ushort*)w1p, (ushort*)w2b, ll);
    gemm1_kernel<<<dim3(HID / 128, MROWS / 128), 256, 0, stream>>>(
        ll, w1p, fc1_b, H, MROWS, HID, C2);
    gemm2_idwt_kernel<<<dim3(C2 / 128, MROWS / 128), 256, 0, stream>>>(
        H, w2b, fc2_b, x, out, MROWS, C2, HID);
}

// Round 3
// 119.666 us; speedup vs baseline: 1.2821x; 1.0325x over previous
//
#include <hip/hip_runtime.h>
#include <hip/hip_bf16.h>
#include <stdint.h>

typedef __bf16 bf16;
typedef __attribute__((ext_vector_type(8))) __bf16 bf16x8;
typedef __attribute__((ext_vector_type(4))) float f32x4;

#define B_DIM 128
#define F_DIM 256
#define C_DIM 512
#define HID   2048
#define F2    (F_DIM/2)      // 128
#define C2    (C_DIM/2)      // 256
#define MROWS (B_DIM*F2)     // 16384

// ---- workspace layout (bytes) ----
static constexpr size_t OFF_W1P = 0;
static constexpr size_t OFF_W2  = OFF_W1P + (size_t)HID * C2 * 2;      // 1,048,576
static constexpr size_t OFF_LL  = OFF_W2  + (size_t)C2 * HID * 2;      // 2,097,152
static constexpr size_t OFF_H   = OFF_LL  + (size_t)MROWS * C2 * 2;    // 10,485,760

__device__ __forceinline__ unsigned short bfbits(float f) {
    bf16 h = (bf16)f;
    return __builtin_bit_cast(unsigned short, h);
}

// async global->LDS, 16B per lane. LDS dest must be linear in lane order.
typedef const __attribute__((address_space(1))) unsigned int as1_uint;
typedef __attribute__((address_space(3))) unsigned int as3_uint;
__device__ __forceinline__ void gld_lds16(const void* g, void* l) {
    as1_uint* gp = (as1_uint*)(uintptr_t)g;
    as3_uint* lp = (as3_uint*)(uintptr_t)l;
    __builtin_amdgcn_global_load_lds(gp, lp, 16, 0, 0);
}

// ---------------- K0: prep — fold interp into W1, cvt W2, DWT(ll) ----------------
__global__ __launch_bounds__(256) void prep_kernel(
    const float* __restrict__ w1, const float* __restrict__ w2,
    const float* __restrict__ x,
    ushort* __restrict__ w1p, ushort* __restrict__ w2b, bf16* __restrict__ ll)
{
    const int blk = blockIdx.x;
    const int t = threadIdx.x;
    if (blk < 2048) {
        int idx = blk * 256 + t;
        int h = idx >> 8, i = idx & 255;
        const float* wrow = w1 + (size_t)h * C_DIM;
        float acc = 0.f;
        int jlo = (i == 0) ? 0 : (int)((float)(i - 1) * (511.0f / 255.0f));
        int jhi = (int)((float)(i + 1) * (511.0f / 255.0f)) + 1;
        if (jhi > 511) jhi = 511;
        for (int j = jlo; j <= jhi; ++j) {
            float pos = (float)j * (255.0f / 511.0f);
            int i0 = (int)pos;
            if (i0 > 254) i0 = 254;
            float w = pos - (float)i0;
            float coef = (i0 == i) ? (1.0f - w) : ((i0 + 1 == i) ? w : 0.0f);
            acc += coef * wrow[j];
        }
        w1p[(size_t)h * C2 + i] = bfbits(acc);
    } else if (blk < 2560) {
        int idx = (blk - 2048) * 256 + t;
        float4 v = ((const float4*)w2)[idx];
        ushort4 u;
        u.x = bfbits(v.x); u.y = bfbits(v.y); u.z = bfbits(v.z); u.w = bfbits(v.w);
        ((ushort4*)w2b)[idx] = u;
    } else {
        int bf = blk - 2560;
        const float* r0 = x + (size_t)(bf >> 7) * F_DIM * C_DIM
                            + (size_t)((bf & 127) * 2) * C_DIM;
        float2 p0 = ((const float2*)r0)[t];
        float2 p1 = ((const float2*)(r0 + C_DIM))[t];
        ll[(size_t)bf * C2 + t] = (bf16)(0.5f * (p0.x + p0.y + p1.x + p1.y));
    }
}

// ---------------- GEMM1: H = GELU(ll * W1'^T + b1), bf16 out ----------------
// 128x128 tile, BK=32, 256 threads = 4 waves (2x2), each wave 64x64 out.
__global__ __launch_bounds__(256) void gemm1_kernel(
    const bf16* __restrict__ A, const bf16* __restrict__ Bw,
    const float* __restrict__ bias, bf16* __restrict__ Cout,
    int M, int N, int K)
{
    __shared__ bf16 As[128][32];
    __shared__ bf16 Bs[128][32];
    const int tid = threadIdx.x;
    const int l = tid & 63;
    const int w = tid >> 6;
    const int wr = w >> 1, wc = w & 1;
    const int row0 = blockIdx.y * 128;
    const int col0 = blockIdx.x * 128;

    f32x4 acc[4][4];
#pragma unroll
    for (int m = 0; m < 4; ++m)
#pragma unroll
        for (int n = 0; n < 4; ++n)
            acc[m][n] = (f32x4){0.f, 0.f, 0.f, 0.f};

    const int lk = (l >> 4) << 3;
    const int lr = l & 15;

    for (int k0 = 0; k0 < K; k0 += 32) {
#pragma unroll
        for (int i = 0; i < 2; ++i) {
            int c = i * 256 + tid;
            int r = c >> 2;
            int cc = (c & 3) << 3;
            gld_lds16(A  + (size_t)(row0 + r) * K + k0 + cc, (bf16*)&As[0][0] + (size_t)c * 8);
            gld_lds16(Bw + (size_t)(col0 + r) * K + k0 + cc, (bf16*)&Bs[0][0] + (size_t)c * 8);
        }
        __syncthreads();
        bf16x8 af[4], bf_[4];
#pragma unroll
        for (int m = 0; m < 4; ++m)
            af[m] = *(const bf16x8*)&As[wr * 64 + m * 16 + lr][lk];
#pragma unroll
        for (int n = 0; n < 4; ++n)
            bf_[n] = *(const bf16x8*)&Bs[wc * 64 + n * 16 + lr][lk];
#pragma unroll
        for (int m = 0; m < 4; ++m)
#pragma unroll
            for (int n = 0; n < 4; ++n)
                acc[m][n] = __builtin_amdgcn_mfma_f32_16x16x32_bf16(af[m], bf_[n], acc[m][n], 0, 0, 0);
        __syncthreads();
    }

    const int rbase = row0 + wr * 64 + ((l >> 4) << 2);
    const int cbase = col0 + wc * 64 + (l & 15);
#pragma unroll
    for (int m = 0; m < 4; ++m) {
#pragma unroll
        for (int n = 0; n < 4; ++n) {
            const int col = cbase + n * 16;
            const float bs = bias[col];
            const int row = rbase + m * 16;
#pragma unroll
            for (int j = 0; j < 4; ++j) {
                float v = acc[m][n][j] + bs;
                float g = 0.5f * v * (1.0f + erff(v * 0.70710678118654752f));
                Cout[(size_t)(row + j) * N + col] = (bf16)g;
            }
        }
    }
}

// ---------------- GEMM2 + fused inverse DWT ----------------
// 64x64 tile, BK=32, 4 waves (2x2), each wave 32x32 out -> grid (4,256)=1024
// blocks = 4 blocks/CU, 4 waves/SIMD (launch_bounds enforces residency).
__global__ __launch_bounds__(256, 4) void gemm2_idwt_kernel(
    const bf16* __restrict__ A, const bf16* __restrict__ Bw,
    const float* __restrict__ bias, const float* __restrict__ x,
    float* __restrict__ out, int M, int N, int K)
{
    __shared__ bf16 As[64][32];
    __shared__ bf16 Bs[64][32];
    const int tid = threadIdx.x;
    const int l = tid & 63;
    const int w = tid >> 6;
    const int wr = w >> 1, wc = w & 1;
    const int row0 = blockIdx.y * 64;
    const int col0 = blockIdx.x * 64;

    f32x4 acc[2][2];
#pragma unroll
    for (int m = 0; m < 2; ++m)
#pragma unroll
        for (int n = 0; n < 2; ++n)
            acc[m][n] = (f32x4){0.f, 0.f, 0.f, 0.f};

    const int lk = (l >> 4) << 3;
    const int lr = l & 15;
    // staging map: chunk c = tid -> row r = c>>2, col (c&3)*8 (16B chunks)
    const int sr = tid >> 2;
    const int sc = (tid & 3) << 3;

    for (int k0 = 0; k0 < K; k0 += 32) {
        gld_lds16(A  + (size_t)(row0 + sr) * K + k0 + sc, (bf16*)&As[0][0] + (size_t)tid * 8);
        gld_lds16(Bw + (size_t)(col0 + sr) * K + k0 + sc, (bf16*)&Bs[0][0] + (size_t)tid * 8);
        __syncthreads();
        bf16x8 af[2], bf_[2];
#pragma unroll
        for (int m = 0; m < 2; ++m)
            af[m] = *(const bf16x8*)&As[wr * 32 + m * 16 + lr][lk];
#pragma unroll
        for (int n = 0; n < 2; ++n)
            bf_[n] = *(const bf16x8*)&Bs[wc * 32 + n * 16 + lr][lk];
#pragma unroll
        for (int m = 0; m < 2; ++m)
#pragma unroll
            for (int n = 0; n < 2; ++n)
                acc[m][n] = __builtin_amdgcn_mfma_f32_16x16x32_bf16(af[m], bf_[n], acc[m][n], 0, 0, 0);
        __syncthreads();
    }

    const int rbase = row0 + wr * 32 + ((l >> 4) << 2);
    const int cbase = col0 + wc * 32 + (l & 15);
#pragma unroll
    for (int m = 0; m < 2; ++m) {
#pragma unroll
        for (int n = 0; n < 2; ++n) {
            const int col = cbase + n * 16;     // c2
            const float bs = bias[col];
#pragma unroll
            for (int j = 0; j < 4; ++j) {
                const int row = rbase + m * 16 + j;   // bf = b*128 + f2
                const int b  = row >> 7;
                const int f2 = row & 127;
                const float* xr0 = x + ((size_t)b * F_DIM + 2 * f2) * C_DIM;
                float2 p0 = ((const float2*)xr0)[col];
                float2 p1 = ((const float2*)(xr0 + C_DIM))[col];
                float a = p0.x, bb = p0.y, c = p1.x, d = p1.y;
                float llv = acc[m][n][j] + bs;
                float lh = 0.5f * (a + bb - c - d);
                float hl = 0.5f * (a - bb + c - d);
                float hh = 0.5f * (a - bb - c + d);
                float2 o0, o1;
                o0.x = 0.5f * (llv + lh + hl + hh);
                o0.y = 0.5f * (llv + lh - hl - hh);
                o1.x = 0.5f * (llv - lh + hl - hh);
                o1.y = 0.5f * (llv - lh - hl + hh);
                float* or0 = out + ((size_t)b * F_DIM + 2 * f2) * C_DIM;
                ((float2*)or0)[col] = o0;
                ((float2*)(or0 + C_DIM))[col] = o1;
            }
        }
    }
}

extern "C" void kernel_launch(void* const* d_in, const int* in_sizes, int n_in,
                              void* d_out, int out_size, void* d_ws, size_t ws_size,
                              hipStream_t stream) {
    const float* x     = (const float*)d_in[0];
    const float* fc1_w = (const float*)d_in[1];
    const float* fc1_b = (const float*)d_in[2];
    const float* fc2_w = (const float*)d_in[3];
    const float* fc2_b = (const float*)d_in[4];
    float* out = (float*)d_out;

    char* ws = (char*)d_ws;
    bf16* w1p = (bf16*)(ws + OFF_W1P);
    bf16* w2b = (bf16*)(ws + OFF_W2);
    bf16* ll  = (bf16*)(ws + OFF_LL);
    bf16* H   = (bf16*)(ws + OFF_H);

    prep_kernel<<<2560 + MROWS, 256, 0, stream>>>(fc1_w, fc2_w, x,
                                                  (ushort*)w1p, (ushort*)w2b, ll);
    gemm1_kernel<<<dim3(HID / 128, MROWS / 128), 256, 0, stream>>>(
        ll, w1p, fc1_b, H, MROWS, HID, C2);
    gemm2_idwt_kernel<<<dim3(C2 / 64, MROWS / 64), 256, 0, stream>>>(
        H, w2b, fc2_b, x, out, MROWS, C2, HID);
}

// Round 4
// 116.046 us; speedup vs baseline: 1.3221x; 1.0312x over previous
//
#include <hip/hip_runtime.h>
#include <hip/hip_bf16.h>
#include <stdint.h>

typedef __bf16 bf16;
typedef __attribute__((ext_vector_type(8))) __bf16 bf16x8;
typedef __attribute__((ext_vector_type(4))) float f32x4;

#define B_DIM 128
#define F_DIM 256
#define C_DIM 512
#define HID   2048
#define F2    (F_DIM/2)      // 128
#define C2    (C_DIM/2)      // 256
#define MROWS (B_DIM*F2)     // 16384

// ---- workspace layout (bytes) ----
static constexpr size_t OFF_W1P = 0;
static constexpr size_t OFF_W2  = OFF_W1P + (size_t)HID * C2 * 2;      // 1,048,576
static constexpr size_t OFF_LL  = OFF_W2  + (size_t)C2 * HID * 2;      // 2,097,152
static constexpr size_t OFF_H   = OFF_LL  + (size_t)MROWS * C2 * 2;    // 10,485,760

__device__ __forceinline__ unsigned short bfbits(float f) {
    bf16 h = (bf16)f;
    return __builtin_bit_cast(unsigned short, h);
}

// async global->LDS, 16B per lane. LDS dest must be linear in lane order.
typedef const __attribute__((address_space(1))) unsigned int as1_uint;
typedef __attribute__((address_space(3))) unsigned int as3_uint;
__device__ __forceinline__ void gld_lds16(const void* g, void* l) {
    as1_uint* gp = (as1_uint*)(uintptr_t)g;
    as3_uint* lp = (as3_uint*)(uintptr_t)l;
    __builtin_amdgcn_global_load_lds(gp, lp, 16, 0, 0);
}

// ---------------- K0: prep — fold interp into W1, cvt W2, DWT(ll) ----------------
__global__ __launch_bounds__(256) void prep_kernel(
    const float* __restrict__ w1, const float* __restrict__ w2,
    const float* __restrict__ x,
    ushort* __restrict__ w1p, ushort* __restrict__ w2b, bf16* __restrict__ ll)
{
    const int blk = blockIdx.x;
    const int t = threadIdx.x;
    if (blk < 2048) {
        int idx = blk * 256 + t;
        int h = idx >> 8, i = idx & 255;
        const float* wrow = w1 + (size_t)h * C_DIM;
        float acc = 0.f;
        int jlo = (i == 0) ? 0 : (int)((float)(i - 1) * (511.0f / 255.0f));
        int jhi = (int)((float)(i + 1) * (511.0f / 255.0f)) + 1;
        if (jhi > 511) jhi = 511;
        for (int j = jlo; j <= jhi; ++j) {
            float pos = (float)j * (255.0f / 511.0f);
            int i0 = (int)pos;
            if (i0 > 254) i0 = 254;
            float w = pos - (float)i0;
            float coef = (i0 == i) ? (1.0f - w) : ((i0 + 1 == i) ? w : 0.0f);
            acc += coef * wrow[j];
        }
        w1p[(size_t)h * C2 + i] = bfbits(acc);
    } else if (blk < 2560) {
        int idx = (blk - 2048) * 256 + t;
        float4 v = ((const float4*)w2)[idx];
        ushort4 u;
        u.x = bfbits(v.x); u.y = bfbits(v.y); u.z = bfbits(v.z); u.w = bfbits(v.w);
        ((ushort4*)w2b)[idx] = u;
    } else {
        int bf = blk - 2560;
        const float* r0 = x + (size_t)(bf >> 7) * F_DIM * C_DIM
                            + (size_t)((bf & 127) * 2) * C_DIM;
        float2 p0 = ((const float2*)r0)[t];
        float2 p1 = ((const float2*)(r0 + C_DIM))[t];
        ll[(size_t)bf * C2 + t] = (bf16)(0.5f * (p0.x + p0.y + p1.x + p1.y));
    }
}

// ---------------- GEMM1: H = GELU(ll * W1'^T + b1), bf16 out ----------------
// 128x128 tile, BK=32, 4 waves (2x2), 2-phase double-buffered pipeline:
// per iter: STAGE(next) || ds_read(cur)+MFMA, then ONE barrier.
__global__ __launch_bounds__(256) void gemm1_kernel(
    const bf16* __restrict__ A, const bf16* __restrict__ Bw,
    const float* __restrict__ bias, bf16* __restrict__ Cout,
    int M, int N, int K)
{
    __shared__ bf16 As[2][128][32];
    __shared__ bf16 Bs[2][128][32];
    const int tid = threadIdx.x;
    const int l = tid & 63;
    const int w = tid >> 6;
    const int wr = w >> 1, wc = w & 1;
    const int row0 = blockIdx.y * 128;
    const int col0 = blockIdx.x * 128;

    f32x4 acc[4][4];
#pragma unroll
    for (int m = 0; m < 4; ++m)
#pragma unroll
        for (int n = 0; n < 4; ++n)
            acc[m][n] = (f32x4){0.f, 0.f, 0.f, 0.f};

    const int lk = (l >> 4) << 3;
    const int lr = l & 15;
    // staging map: chunk c -> row c>>2, 16B col (c&3)*8
    const int sr = tid >> 2;
    const int sc = (tid & 3) << 3;

    // prologue: stage buffer 0
#pragma unroll
    for (int i = 0; i < 2; ++i) {
        int c = i * 256 + tid;
        gld_lds16(A  + (size_t)(row0 + (c >> 2)) * K + ((c & 3) << 3),
                  (bf16*)&As[0][0][0] + (size_t)c * 8);
        gld_lds16(Bw + (size_t)(col0 + (c >> 2)) * K + ((c & 3) << 3),
                  (bf16*)&Bs[0][0][0] + (size_t)c * 8);
    }
    __syncthreads();

    const int NT = K >> 5;
    for (int t = 0; t < NT; ++t) {
        const int cur = t & 1;
        if (t + 1 < NT) {
            const int k0 = (t + 1) << 5;
#pragma unroll
            for (int i = 0; i < 2; ++i) {
                int c = i * 256 + tid;
                gld_lds16(A  + (size_t)(row0 + (c >> 2)) * K + k0 + ((c & 3) << 3),
                          (bf16*)&As[cur ^ 1][0][0] + (size_t)c * 8);
                gld_lds16(Bw + (size_t)(col0 + (c >> 2)) * K + k0 + ((c & 3) << 3),
                          (bf16*)&Bs[cur ^ 1][0][0] + (size_t)c * 8);
            }
        }
        bf16x8 af[4], bf_[4];
#pragma unroll
        for (int m = 0; m < 4; ++m)
            af[m] = *(const bf16x8*)&As[cur][wr * 64 + m * 16 + lr][lk];
#pragma unroll
        for (int n = 0; n < 4; ++n)
            bf_[n] = *(const bf16x8*)&Bs[cur][wc * 64 + n * 16 + lr][lk];
#pragma unroll
        for (int m = 0; m < 4; ++m)
#pragma unroll
            for (int n = 0; n < 4; ++n)
                acc[m][n] = __builtin_amdgcn_mfma_f32_16x16x32_bf16(af[m], bf_[n], acc[m][n], 0, 0, 0);
        __syncthreads();   // implicit vmcnt(0)+lgkmcnt(0) drain: next buffer ready
    }

    const int rbase = row0 + wr * 64 + ((l >> 4) << 2);
    const int cbase = col0 + wc * 64 + (l & 15);
#pragma unroll
    for (int m = 0; m < 4; ++m) {
#pragma unroll
        for (int n = 0; n < 4; ++n) {
            const int col = cbase + n * 16;
            const float bs = bias[col];
            const int row = rbase + m * 16;
#pragma unroll
            for (int j = 0; j < 4; ++j) {
                float v = acc[m][n][j] + bs;
                float g = 0.5f * v * (1.0f + erff(v * 0.70710678118654752f));
                Cout[(size_t)(row + j) * N + col] = (bf16)g;
            }
        }
    }
}

// ---------------- GEMM2 + fused inverse DWT ----------------
// 64x64 tile, BK=32, 4 waves (2x2), 2-phase double-buffered, 4 blocks/CU.
__global__ __launch_bounds__(256, 4) void gemm2_idwt_kernel(
    const bf16* __restrict__ A, const bf16* __restrict__ Bw,
    const float* __restrict__ bias, const float* __restrict__ x,
    float* __restrict__ out, int M, int N, int K)
{
    __shared__ bf16 As[2][64][32];
    __shared__ bf16 Bs[2][64][32];
    const int tid = threadIdx.x;
    const int l = tid & 63;
    const int w = tid >> 6;
    const int wr = w >> 1, wc = w & 1;
    const int row0 = blockIdx.y * 64;
    const int col0 = blockIdx.x * 64;

    f32x4 acc[2][2];
#pragma unroll
    for (int m = 0; m < 2; ++m)
#pragma unroll
        for (int n = 0; n < 2; ++n)
            acc[m][n] = (f32x4){0.f, 0.f, 0.f, 0.f};

    const int lk = (l >> 4) << 3;
    const int lr = l & 15;
    const int sr = tid >> 2;
    const int sc = (tid & 3) << 3;

    // prologue: stage buffer 0
    gld_lds16(A  + (size_t)(row0 + sr) * K + sc, (bf16*)&As[0][0][0] + (size_t)tid * 8);
    gld_lds16(Bw + (size_t)(col0 + sr) * K + sc, (bf16*)&Bs[0][0][0] + (size_t)tid * 8);
    __syncthreads();

    const int NT = K >> 5;
    for (int t = 0; t < NT; ++t) {
        const int cur = t & 1;
        if (t + 1 < NT) {
            const int k0 = (t + 1) << 5;
            gld_lds16(A  + (size_t)(row0 + sr) * K + k0 + sc,
                      (bf16*)&As[cur ^ 1][0][0] + (size_t)tid * 8);
            gld_lds16(Bw + (size_t)(col0 + sr) * K + k0 + sc,
                      (bf16*)&Bs[cur ^ 1][0][0] + (size_t)tid * 8);
        }
        bf16x8 af[2], bf_[2];
#pragma unroll
        for (int m = 0; m < 2; ++m)
            af[m] = *(const bf16x8*)&As[cur][wr * 32 + m * 16 + lr][lk];
#pragma unroll
        for (int n = 0; n < 2; ++n)
            bf_[n] = *(const bf16x8*)&Bs[cur][wc * 32 + n * 16 + lr][lk];
#pragma unroll
        for (int m = 0; m < 2; ++m)
#pragma unroll
            for (int n = 0; n < 2; ++n)
                acc[m][n] = __builtin_amdgcn_mfma_f32_16x16x32_bf16(af[m], bf_[n], acc[m][n], 0, 0, 0);
        __syncthreads();
    }

    const int rbase = row0 + wr * 32 + ((l >> 4) << 2);
    const int cbase = col0 + wc * 32 + (l & 15);
#pragma unroll
    for (int m = 0; m < 2; ++m) {
#pragma unroll
        for (int n = 0; n < 2; ++n) {
            const int col = cbase + n * 16;     // c2
            const float bs = bias[col];
#pragma unroll
            for (int j = 0; j < 4; ++j) {
                const int row = rbase + m * 16 + j;   // bf = b*128 + f2
                const int b  = row >> 7;
                const int f2 = row & 127;
                const float* xr0 = x + ((size_t)b * F_DIM + 2 * f2) * C_DIM;
                float2 p0 = ((const float2*)xr0)[col];
                float2 p1 = ((const float2*)(xr0 + C_DIM))[col];
                float a = p0.x, bb = p0.y, c = p1.x, d = p1.y;
                float llv = acc[m][n][j] + bs;
                float lh = 0.5f * (a + bb - c - d);
                float hl = 0.5f * (a - bb + c - d);
                float hh = 0.5f * (a - bb - c + d);
                float2 o0, o1;
                o0.x = 0.5f * (llv + lh + hl + hh);
                o0.y = 0.5f * (llv + lh - hl - hh);
                o1.x = 0.5f * (llv - lh + hl - hh);
                o1.y = 0.5f * (llv - lh - hl + hh);
                float* or0 = out + ((size_t)b * F_DIM + 2 * f2) * C_DIM;
                ((float2*)or0)[col] = o0;
                ((float2*)(or0 + C_DIM))[col] = o1;
            }
        }
    }
}

extern "C" void kernel_launch(void* const* d_in, const int* in_sizes, int n_in,
                              void* d_out, int out_size, void* d_ws, size_t ws_size,
                              hipStream_t stream) {
    const float* x     = (const float*)d_in[0];
    const float* fc1_w = (const float*)d_in[1];
    const float* fc1_b = (const float*)d_in[2];
    const float* fc2_w = (const float*)d_in[3];
    const float* fc2_b = (const float*)d_in[4];
    float* out = (float*)d_out;

    char* ws = (char*)d_ws;
    bf16* w1p = (bf16*)(ws + OFF_W1P);
    bf16* w2b = (bf16*)(ws + OFF_W2);
    bf16* ll  = (bf16*)(ws + OFF_LL);
    bf16* H   = (bf16*)(ws + OFF_H);

    prep_kernel<<<2560 + MROWS, 256, 0, stream>>>(fc1_w, fc2_w, x,
                                                  (ushort*)w1p, (ushort*)w2b, ll);
    gemm1_kernel<<<dim3(HID / 128, MROWS / 128), 256, 0, stream>>>(
        ll, w1p, fc1_b, H, MROWS, HID, C2);
    gemm2_idwt_kernel<<<dim3(C2 / 64, MROWS / 64), 256, 0, stream>>>(
        H, w2b, fc2_b, x, out, MROWS, C2, HID);
}

// Round 5
// 107.568 us; speedup vs baseline: 1.4263x; 1.0788x over previous
//
#include <hip/hip_runtime.h>
#include <hip/hip_bf16.h>
#include <stdint.h>

typedef __bf16 bf16;
typedef __attribute__((ext_vector_type(8))) __bf16 bf16x8;
typedef __attribute__((ext_vector_type(4))) float f32x4;

#define B_DIM 128
#define F_DIM 256
#define C_DIM 512
#define HID   2048
#define F2    (F_DIM/2)      // 128
#define C2    (C_DIM/2)      // 256
#define MROWS (B_DIM*F2)     // 16384

// ---- workspace: W1P bf16[2048][256] @0 ; W2b bf16[256][2048] @1MB ----
static constexpr size_t OFF_W1P = 0;
static constexpr size_t OFF_W2  = OFF_W1P + (size_t)HID * C2 * 2;   // 1,048,576

__device__ __forceinline__ unsigned short bfbits(float f) {
    bf16 h = (bf16)f;
    return __builtin_bit_cast(unsigned short, h);
}

// async global->LDS, 16B per lane. LDS dest must be lane-linear.
typedef const __attribute__((address_space(1))) unsigned int as1_uint;
typedef __attribute__((address_space(3))) unsigned int as3_uint;
__device__ __forceinline__ void gld_lds16(const void* g, void* l) {
    as1_uint* gp = (as1_uint*)(uintptr_t)g;
    as3_uint* lp = (as3_uint*)(uintptr_t)l;
    __builtin_amdgcn_global_load_lds(gp, lp, 16, 0, 0);
}

#define VMCNT2() asm volatile("s_waitcnt vmcnt(2)" ::: "memory")
#define VMCNT0() asm volatile("s_waitcnt vmcnt(0)" ::: "memory")

// ---------------- K0: prep — fold interp into W1 (bf16), cvt W2 (bf16) ----------------
__global__ __launch_bounds__(256) void prep_kernel(
    const float* __restrict__ w1, const float* __restrict__ w2,
    ushort* __restrict__ w1p, ushort* __restrict__ w2b)
{
    const int blk = blockIdx.x;
    const int t = threadIdx.x;
    if (blk < 2048) {
        int idx = blk * 256 + t;
        int h = idx >> 8, i = idx & 255;
        const float* wrow = w1 + (size_t)h * C_DIM;
        float acc = 0.f;
        int jlo = (i == 0) ? 0 : (int)((float)(i - 1) * (511.0f / 255.0f));
        int jhi = (int)((float)(i + 1) * (511.0f / 255.0f)) + 1;
        if (jhi > 511) jhi = 511;
        for (int j = jlo; j <= jhi; ++j) {
            float pos = (float)j * (255.0f / 511.0f);
            int i0 = (int)pos;
            if (i0 > 254) i0 = 254;
            float w = pos - (float)i0;
            float coef = (i0 == i) ? (1.0f - w) : ((i0 + 1 == i) ? w : 0.0f);
            acc += coef * wrow[j];
        }
        w1p[(size_t)h * C2 + i] = bfbits(acc);
    } else {
        int idx = (blk - 2048) * 256 + t;      // 0..131071 float4s
        float4 v = ((const float4*)w2)[idx];
        ushort4 u;
        u.x = bfbits(v.x); u.y = bfbits(v.y); u.z = bfbits(v.z); u.w = bfbits(v.w);
        ((ushort4*)w2b)[idx] = u;
    }
}

// ---------------- fused: DWT(ll) -> [GEMM1+GELU -> GEMM2]x8 chunks -> iDWT ----------------
// 512 blocks x 512 threads (8 waves, 2Mx4N). 32 output rows per block.
// LDS 64KB: ll_s[32][256] swz | Hs[32][256] swz | Bst dbuf 2x[256][32] swz.
__global__ __launch_bounds__(512, 4) void fused_mlp(
    const bf16* __restrict__ w1p, const bf16* __restrict__ w2b,
    const float* __restrict__ b1, const float* __restrict__ b2,
    const float* __restrict__ x, float* __restrict__ out)
{
    __shared__ __align__(16) char smem[65536];
    bf16* Bst0 = (bf16*)(smem + 32768);
    bf16* Bst1 = (bf16*)(smem + 49152);

    const int tid = threadIdx.x;
    const int l   = tid & 63;
    const int wv  = tid >> 6;          // 0..7
    const int wm  = wv >> 2;           // 0..1  (16 rows each)
    const int wn  = wv & 3;            // 0..3  (64 cols each)
    const int lr  = l & 15;
    const int q   = l >> 4;            // 0..3
    const int R0  = blockIdx.x * 32;   // block row base (bf)
    const int e7  = lr & 7;
    const int qb  = ((q ^ (lr & 3)) << 4);   // swizzled B-frag slot byte

    // stage a 256x32 bf16 tile (16KB), source pre-swizzled so reads can XOR
    auto stageB1 = [&](int hc, int t, bf16* buf) {
#pragma unroll
        for (int i = 0; i < 2; ++i) {
            int c = i * 512 + tid; int r = c >> 2; int sl = (c & 3) ^ (r & 3);
            gld_lds16(w1p + (size_t)(hc * 256 + r) * 256 + t * 32 + sl * 8,
                      (char*)buf + c * 16);
        }
    };
    auto stageB2 = [&](int hc, int t, bf16* buf) {
#pragma unroll
        for (int i = 0; i < 2; ++i) {
            int c = i * 512 + tid; int r = c >> 2; int sl = (c & 3) ^ (r & 3);
            gld_lds16(w2b + (size_t)r * 2048 + hc * 256 + t * 32 + sl * 8,
                      (char*)buf + c * 16);
        }
    };

    stageB1(0, 0, Bst0);               // first W1' tile in flight under ll phase

    // ---- ll phase: DWT from x into LDS (swizzled bf16 [32][256]) ----
#pragma unroll
    for (int k = 0; k < 16; ++k) {
        int o = tid + k * 512;
        int r = o >> 8, c2 = o & 255;
        int gbf = R0 + r;
        const float* xr = x + ((size_t)(gbf >> 7) * F_DIM + (size_t)(gbf & 127) * 2) * C_DIM;
        float2 p0 = ((const float2*)xr)[c2];
        float2 p1 = ((const float2*)(xr + C_DIM))[c2];
        float v = 0.5f * (p0.x + p0.y + p1.x + p1.y);
        int by = (r * 512 + c2 * 2) ^ ((r & 7) << 4);
        *(bf16*)(smem + by) = (bf16)v;
    }
    __syncthreads();   // drains vmcnt: ll_s + B1(0,0) all landed

    f32x4 acc2[4];
#pragma unroll
    for (int n = 0; n < 4; ++n) acc2[n] = (f32x4){0.f, 0.f, 0.f, 0.f};

    for (int hc = 0; hc < 8; ++hc) {
        f32x4 acc1[4];
#pragma unroll
        for (int n = 0; n < 4; ++n) acc1[n] = (f32x4){0.f, 0.f, 0.f, 0.f};

        // ---- GEMM1: S1[32][256] = ll_s @ W1P[hc]^T ----
#pragma unroll
        for (int t = 0; t < 8; ++t) {
            bf16* cur = (t & 1) ? Bst1 : Bst0;
            if (t < 7) stageB1(hc, t + 1, (t & 1) ? Bst0 : Bst1);
            else       stageB2(hc, 0, Bst0);        // next loop's first tile
            VMCNT2();                                // tile t landed; t+1 in flight
            __builtin_amdgcn_s_barrier();
            __builtin_amdgcn_sched_barrier(0);
            bf16x8 af = *(const bf16x8*)(smem +
                ((wm * 16 + lr) * 512 + ((((t << 2) + q) ^ e7) << 4)));
            bf16x8 bfr[4];
#pragma unroll
            for (int n = 0; n < 4; ++n)
                bfr[n] = *(const bf16x8*)((char*)cur + ((wn * 64 + n * 16 + lr) * 64 + qb));
#pragma unroll
            for (int n = 0; n < 4; ++n)
                acc1[n] = __builtin_amdgcn_mfma_f32_16x16x32_bf16(af, bfr[n], acc1[n], 0, 0, 0);
            __builtin_amdgcn_sched_barrier(0);
            __builtin_amdgcn_s_barrier();            // readers done before overwrite
        }

        // ---- GELU -> Hs (swizzled bf16 [32][256] @ +16384) ----
#pragma unroll
        for (int n = 0; n < 4; ++n) {
            int col = wn * 64 + n * 16 + lr;
            float bs = b1[hc * 256 + col];
#pragma unroll
            for (int j = 0; j < 4; ++j) {
                float v = acc1[n][j] + bs;
                float tt = v * (0.79788456080f + 0.03567740814f * v * v);
                float e = __expf(-2.0f * tt);
                float g = v / (1.0f + e);            // v * sigmoid(2t)
                int row = wm * 16 + q * 4 + j;
                int by = 16384 + ((row * 512 + col * 2) ^ ((row & 7) << 4));
                *(bf16*)(smem + by) = (bf16)g;
            }
        }
        __syncthreads();   // Hs visible; drains B2(hc,0) (landed under GELU)

        // ---- GEMM2: acc2 += Hs @ W2[:, hc-chunk]^T ----
#pragma unroll
        for (int t = 0; t < 8; ++t) {
            bf16* cur = (t & 1) ? Bst1 : Bst0;
            if (t < 7)          stageB2(hc, t + 1, (t & 1) ? Bst0 : Bst1);
            else if (hc < 7)    stageB1(hc + 1, 0, Bst0);   // next chunk's first tile
            if (t == 7 && hc == 7) { VMCNT0(); } else { VMCNT2(); }
            __builtin_amdgcn_s_barrier();
            __builtin_amdgcn_sched_barrier(0);
            bf16x8 af = *(const bf16x8*)(smem + 16384 +
                ((wm * 16 + lr) * 512 + ((((t << 2) + q) ^ e7) << 4)));
            bf16x8 bfr[4];
#pragma unroll
            for (int n = 0; n < 4; ++n)
                bfr[n] = *(const bf16x8*)((char*)cur + ((wn * 64 + n * 16 + lr) * 64 + qb));
#pragma unroll
            for (int n = 0; n < 4; ++n)
                acc2[n] = __builtin_amdgcn_mfma_f32_16x16x32_bf16(af, bfr[n], acc2[n], 0, 0, 0);
            __builtin_amdgcn_sched_barrier(0);
            __builtin_amdgcn_s_barrier();
        }
    }

    // ---- epilogue: bias + iDWT (recompute lh/hl/hh from x) -> out ----
#pragma unroll
    for (int n = 0; n < 4; ++n) {
        int c2 = wn * 64 + n * 16 + lr;
        float bs = b2[c2];
#pragma unroll
        for (int j = 0; j < 4; ++j) {
            int gbf = R0 + wm * 16 + q * 4 + j;
            int b = gbf >> 7, f2 = gbf & 127;
            const float* xr = x + ((size_t)b * F_DIM + (size_t)f2 * 2) * C_DIM;
            float2 p0 = ((const float2*)xr)[c2];
            float2 p1 = ((const float2*)(xr + C_DIM))[c2];
            float a = p0.x, bb = p0.y, cc = p1.x, dd = p1.y;
            float llv = acc2[n][j] + bs;
            float lh = 0.5f * (a + bb - cc - dd);
            float hl = 0.5f * (a - bb + cc - dd);
            float hh = 0.5f * (a - bb - cc + dd);
            float2 o0, o1;
            o0.x = 0.5f * (llv + lh + hl + hh);
            o0.y = 0.5f * (llv + lh - hl - hh);
            o1.x = 0.5f * (llv - lh + hl - hh);
            o1.y = 0.5f * (llv - lh - hl + hh);
            float* orow = out + ((size_t)b * F_DIM + (size_t)f2 * 2) * C_DIM;
            ((float2*)orow)[c2] = o0;
            ((float2*)(orow + C_DIM))[c2] = o1;
        }
    }
}

extern "C" void kernel_launch(void* const* d_in, const int* in_sizes, int n_in,
                              void* d_out, int out_size, void* d_ws, size_t ws_size,
                              hipStream_t stream) {
    const float* x     = (const float*)d_in[0];
    const float* fc1_w = (const float*)d_in[1];
    const float* fc1_b = (const float*)d_in[2];
    const float* fc2_w = (const float*)d_in[3];
    const float* fc2_b = (const float*)d_in[4];
    float* out = (float*)d_out;

    char* ws = (char*)d_ws;
    bf16* w1p = (bf16*)(ws + OFF_W1P);
    bf16* w2b = (bf16*)(ws + OFF_W2);

    prep_kernel<<<2560, 256, 0, stream>>>(fc1_w, fc2_w, (ushort*)w1p, (ushort*)w2b);
    fused_mlp<<<MROWS / 32, 512, 0, stream>>>(w1p, w2b, fc1_b, fc2_b, x, out);
}

// Round 6
// 99.939 us; speedup vs baseline: 1.5352x; 1.0763x over previous
//
#include <hip/hip_runtime.h>
#include <hip/hip_bf16.h>
#include <stdint.h>

typedef __bf16 bf16;
typedef __attribute__((ext_vector_type(8))) __bf16 bf16x8;
typedef __attribute__((ext_vector_type(4))) float f32x4;

#define B_DIM 128
#define F_DIM 256
#define C_DIM 512
#define HID   2048
#define F2    (F_DIM/2)      // 128
#define C2    (C_DIM/2)      // 256
#define MROWS (B_DIM*F2)     // 16384

// ---- workspace: fragment-packed weights ----
// w1pp: [hblk 0..127][t 0..7][lane 0..63][e 0..7] bf16  (1 MB)
//        value = W1P[hblk*16 + (lane&15)][t*32 + (lane>>4)*8 + e]
// w2pp: [c2blk 0..15][kblk 0..63][lane 0..63][e 0..7] bf16 (1 MB)
//        value = fc2_w[c2blk*16 + (lane&15)][kblk*32 + (lane>>4)*8 + e]
static constexpr size_t OFF_W1P = 0;
static constexpr size_t OFF_W2  = OFF_W1P + (size_t)HID * C2 * 2;   // 1,048,576

__device__ __forceinline__ unsigned short bfbits(float f) {
    bf16 h = (bf16)f;
    return __builtin_bit_cast(unsigned short, h);
}

// ---------------- K0: prep — fold interp into W1, pack both weights ----------------
__global__ __launch_bounds__(256) void prep_kernel(
    const float* __restrict__ w1, const float* __restrict__ w2,
    bf16* __restrict__ w1pp, bf16* __restrict__ w2pp)
{
    const int blk = blockIdx.x;
    const int t = threadIdx.x;
    if (blk < 2048) {
        int idx = blk * 256 + t;
        int h = idx >> 8, k = idx & 255;
        const float* wrow = w1 + (size_t)h * C_DIM;
        float acc = 0.f;
        int jlo = (k == 0) ? 0 : (int)((float)(k - 1) * (511.0f / 255.0f));
        int jhi = (int)((float)(k + 1) * (511.0f / 255.0f)) + 1;
        if (jhi > 511) jhi = 511;
        for (int j = jlo; j <= jhi; ++j) {
            float pos = (float)j * (255.0f / 511.0f);
            int i0 = (int)pos;
            if (i0 > 254) i0 = 254;
            float w = pos - (float)i0;
            float coef = (i0 == k) ? (1.0f - w) : ((i0 + 1 == k) ? w : 0.0f);
            acc += coef * wrow[j];
        }
        // pack: lane = ((k>>3)&3)<<4 | (h&15)
        size_t off = ((((size_t)(h >> 4)) * 8 + (k >> 5)) * 64
                      + ((((k >> 3) & 3) << 4) | (h & 15))) * 8 + (k & 7);
        w1pp[off] = (bf16)acc;
    } else {
        int idx2 = (blk - 2048) * 256 + t;     // 0..524287
        int c2 = idx2 >> 11, h = idx2 & 2047;
        float v = w2[(size_t)c2 * HID + h];
        size_t off = ((((size_t)(c2 >> 4)) * 64 + (h >> 5)) * 64
                      + ((((h >> 3) & 3) << 4) | (c2 & 15))) * 8 + (h & 7);
        w2pp[off] = (bf16)v;
    }
}

// ---------------- fused: DWT -> [GEMM1+GELU -> GEMM2]x8 -> iDWT ----------------
// 512 blocks x 512 threads (8 waves). Block owns 32 rows (bf). Wave wn owns 32 c2/hid cols.
// LDS 32KB: ll_pack [2][8][64][8] bf16 (16KB) | Hs_pack same (16KB). All frag reads
// are linear lane*16B (conflict-free); weights come straight from L2 in packed order.
__global__ __launch_bounds__(512, 4) void fused_mlp(
    const bf16* __restrict__ w1pp, const bf16* __restrict__ w2pp,
    const float* __restrict__ b1, const float* __restrict__ b2,
    const float* __restrict__ x, float* __restrict__ out)
{
    __shared__ __align__(16) char smem[32768];

    const int tid = threadIdx.x;
    const int l   = tid & 63;
    const int wn  = tid >> 6;          // 0..7: cols wn*32..+32
    const int lr  = l & 15;
    const int q   = l >> 4;            // 0..3
    const int R0  = blockIdx.x * 32;

    // ---- DWT phase: fill ll_pack (fragment order) ----
    {
        const int rr = tid >> 4;               // 0..31 row
        const int w0 = tid & 15;
        const int gbf = R0 + rr;
        const float* xr = x + ((size_t)(gbf >> 7) * F_DIM + (size_t)(gbf & 127) * 2) * C_DIM;
        const float* xs = xr + C_DIM;
#pragma unroll
        for (int half = 0; half < 2; ++half) {
            const int w = w0 + half * 16;      // 16B slot in row: c2 = w*8..+7
            float4 ra[4], rb[4];
#pragma unroll
            for (int i = 0; i < 4; ++i) {
                ra[i] = ((const float4*)xr)[w * 4 + i];
                rb[i] = ((const float4*)xs)[w * 4 + i];
            }
            const float* pa = (const float*)ra;
            const float* pb = (const float*)rb;
            bf16x8 pk;
#pragma unroll
            for (int e = 0; e < 8; ++e)
                pk[e] = (bf16)(0.5f * (pa[2*e] + pa[2*e+1] + pb[2*e] + pb[2*e+1]));
            // packed slot: wm'=rr>>4, t'=w>>2, q'=w&3, lr'=rr&15
            int slot = (((rr >> 4) * 8 + (w >> 2)) * 64) + ((w & 3) << 4) + (rr & 15);
            *(bf16x8*)(smem + slot * 16) = pk;
        }
    }
    __syncthreads();

    f32x4 acc2[2][2];
#pragma unroll
    for (int m = 0; m < 2; ++m)
#pragma unroll
        for (int n = 0; n < 2; ++n)
            acc2[m][n] = (f32x4){0.f, 0.f, 0.f, 0.f};

    for (int hc = 0; hc < 8; ++hc) {
        // ---- GEMM1: S1[32][32 cols of this wave] over K=256, no barriers ----
        f32x4 acc1[2][2];
#pragma unroll
        for (int m = 0; m < 2; ++m)
#pragma unroll
            for (int n = 0; n < 2; ++n)
                acc1[m][n] = (f32x4){0.f, 0.f, 0.f, 0.f};

#pragma unroll
        for (int t = 0; t < 8; ++t) {
            bf16x8 af[2];
#pragma unroll
            for (int m = 0; m < 2; ++m)
                af[m] = *(const bf16x8*)(smem + ((m * 8 + t) * 64 + l) * 16);
#pragma unroll
            for (int n = 0; n < 2; ++n) {
                const int hblk = hc * 16 + wn * 2 + n;
                bf16x8 bw = *(const bf16x8*)(w1pp + (((size_t)hblk * 8 + t) * 64 + l) * 8);
#pragma unroll
                for (int m = 0; m < 2; ++m)
                    acc1[m][n] = __builtin_amdgcn_mfma_f32_16x16x32_bf16(af[m], bw, acc1[m][n], 0, 0, 0);
            }
        }

        // ---- GELU -> Hs_pack ----
#pragma unroll
        for (int n = 0; n < 2; ++n) {
            const int col = wn * 32 + n * 16 + lr;       // hid within chunk
            const float bs = b1[hc * 256 + col];
            const int t2 = col >> 5, qq = (col >> 3) & 3, e = col & 7;
#pragma unroll
            for (int m = 0; m < 2; ++m) {
#pragma unroll
                for (int j = 0; j < 4; ++j) {
                    float v = acc1[m][n][j] + bs;
                    float tt = v * (0.79788456080f + 0.03567740814f * v * v);
                    float ex = __expf(-2.0f * tt);
                    float g = v / (1.0f + ex);           // v * sigmoid(2t)
                    const int row = m * 16 + q * 4 + j;
                    int off = ((m * 8 + t2) * 64 + (qq << 4) + (row & 15)) * 8 + e;
                    *(bf16*)(smem + 16384 + off * 2) = (bf16)g;
                }
            }
        }
        __syncthreads();   // Hs complete, visible to all waves

        // ---- GEMM2: acc2 += Hs @ W2chunk^T, no barriers ----
#pragma unroll
        for (int t = 0; t < 8; ++t) {
            bf16x8 af[2];
#pragma unroll
            for (int m = 0; m < 2; ++m)
                af[m] = *(const bf16x8*)(smem + 16384 + ((m * 8 + t) * 64 + l) * 16);
#pragma unroll
            for (int n = 0; n < 2; ++n) {
                const int c2blk = wn * 2 + n;
                bf16x8 bw = *(const bf16x8*)(w2pp + (((size_t)c2blk * 64 + hc * 8 + t) * 64 + l) * 8);
#pragma unroll
                for (int m = 0; m < 2; ++m)
                    acc2[m][n] = __builtin_amdgcn_mfma_f32_16x16x32_bf16(af[m], bw, acc2[m][n], 0, 0, 0);
            }
        }
        __syncthreads();   // all waves done reading Hs before next GELU overwrites
    }

    // ---- epilogue: bias + iDWT (recompute lh/hl/hh from x) -> out ----
#pragma unroll
    for (int n = 0; n < 2; ++n) {
        const int c2 = wn * 32 + n * 16 + lr;
        const float bs = b2[c2];
#pragma unroll
        for (int m = 0; m < 2; ++m) {
#pragma unroll
            for (int j = 0; j < 4; ++j) {
                const int gbf = R0 + m * 16 + q * 4 + j;
                const int b = gbf >> 7, f2 = gbf & 127;
                const float* xr = x + ((size_t)b * F_DIM + (size_t)f2 * 2) * C_DIM;
                float2 p0 = ((const float2*)xr)[c2];
                float2 p1 = ((const float2*)(xr + C_DIM))[c2];
                float a = p0.x, bb = p0.y, cc = p1.x, dd = p1.y;
                float llv = acc2[m][n][j] + bs;
                float lh = 0.5f * (a + bb - cc - dd);
                float hl = 0.5f * (a - bb + cc - dd);
                float hh = 0.5f * (a - bb - cc + dd);
                float2 o0, o1;
                o0.x = 0.5f * (llv + lh + hl + hh);
                o0.y = 0.5f * (llv + lh - hl - hh);
                o1.x = 0.5f * (llv - lh + hl - hh);
                o1.y = 0.5f * (llv - lh - hl + hh);
                float* orow = out + ((size_t)b * F_DIM + (size_t)f2 * 2) * C_DIM;
                ((float2*)orow)[c2] = o0;
                ((float2*)(orow + C_DIM))[c2] = o1;
            }
        }
    }
}

extern "C" void kernel_launch(void* const* d_in, const int* in_sizes, int n_in,
                              void* d_out, int out_size, void* d_ws, size_t ws_size,
                              hipStream_t stream) {
    const float* x     = (const float*)d_in[0];
    const float* fc1_w = (const float*)d_in[1];
    const float* fc1_b = (const float*)d_in[2];
    const float* fc2_w = (const float*)d_in[3];
    const float* fc2_b = (const float*)d_in[4];
    float* out = (float*)d_out;

    char* ws = (char*)d_ws;
    bf16* w1pp = (bf16*)(ws + OFF_W1P);
    bf16* w2pp = (bf16*)(ws + OFF_W2);

    prep_kernel<<<4096, 256, 0, stream>>>(fc1_w, fc2_w, w1pp, w2pp);
    fused_mlp<<<MROWS / 32, 512, 0, stream>>>(w1pp, w2pp, fc1_b, fc2_b, x, out);
}

// Round 7
// 94.822 us; speedup vs baseline: 1.6180x; 1.0540x over previous
//
#include <hip/hip_runtime.h>
#include <hip/hip_bf16.h>
#include <stdint.h>

typedef __bf16 bf16;
typedef __attribute__((ext_vector_type(8))) __bf16 bf16x8;
typedef __attribute__((ext_vector_type(4))) float f32x4;

#define B_DIM 128
#define F_DIM 256
#define C_DIM 512
#define HID   2048
#define F2    (F_DIM/2)      // 128
#define C2    (C_DIM/2)      // 256
#define MROWS (B_DIM*F2)     // 16384

// ---- workspace: fragment-packed weights ----
// w1pp: [hblk 0..127][t 0..7][lane 0..63][e 0..7] bf16  (1 MB)
//        value = W1P[hblk*16 + (lane&15)][t*32 + (lane>>4)*8 + e]
// w2pp: [c2blk 0..15][kblk 0..63][lane 0..63][e 0..7] bf16 (1 MB)
//        value = fc2_w[c2blk*16 + (lane&15)][kblk*32 + (lane>>4)*8 + e]
static constexpr size_t OFF_W1P = 0;
static constexpr size_t OFF_W2  = OFF_W1P + (size_t)HID * C2 * 2;   // 1,048,576

__device__ __forceinline__ unsigned short bfbits(float f) {
    bf16 h = (bf16)f;
    return __builtin_bit_cast(unsigned short, h);
}

// ---------------- K0: prep — fold interp into W1, pack both weights ----------------
__global__ __launch_bounds__(256) void prep_kernel(
    const float* __restrict__ w1, const float* __restrict__ w2,
    bf16* __restrict__ w1pp, bf16* __restrict__ w2pp)
{
    const int blk = blockIdx.x;
    const int t = threadIdx.x;
    if (blk < 2048) {
        int idx = blk * 256 + t;
        int h = idx >> 8, k = idx & 255;
        const float* wrow = w1 + (size_t)h * C_DIM;
        float acc = 0.f;
        int jlo = (k == 0) ? 0 : (int)((float)(k - 1) * (511.0f / 255.0f));
        int jhi = (int)((float)(k + 1) * (511.0f / 255.0f)) + 1;
        if (jhi > 511) jhi = 511;
        for (int j = jlo; j <= jhi; ++j) {
            float pos = (float)j * (255.0f / 511.0f);
            int i0 = (int)pos;
            if (i0 > 254) i0 = 254;
            float w = pos - (float)i0;
            float coef = (i0 == k) ? (1.0f - w) : ((i0 + 1 == k) ? w : 0.0f);
            acc += coef * wrow[j];
        }
        size_t off = ((((size_t)(h >> 4)) * 8 + (k >> 5)) * 64
                      + ((((k >> 3) & 3) << 4) | (h & 15))) * 8 + (k & 7);
        w1pp[off] = (bf16)acc;
    } else {
        int idx2 = (blk - 2048) * 256 + t;     // 0..524287
        int c2 = idx2 >> 11, h = idx2 & 2047;
        float v = w2[(size_t)c2 * HID + h];
        size_t off = ((((size_t)(c2 >> 4)) * 64 + (h >> 5)) * 64
                      + ((((h >> 3) & 3) << 4) | (c2 & 15))) * 8 + (h & 7);
        w2pp[off] = (bf16)v;
    }
}

// ---------------- fused: DWT -> [GEMM1+GELU -> GEMM2]x8 -> iDWT ----------------
// 512 blocks x 512 threads (8 waves). Block owns 32 rows. Wave wn owns 32 cols.
// Weights fragment-packed in global (L2-resident); per GEMM phase ALL 16 weight
// frags are prefetched into registers (16 loads in flight -> one L2 latency per
// phase, not 16). LDS 32KB: ll_pack 16KB | Hs_pack 16KB, all reads lane-linear.
__global__ __launch_bounds__(512, 4) void fused_mlp(
    const bf16* __restrict__ w1pp, const bf16* __restrict__ w2pp,
    const float* __restrict__ b1, const float* __restrict__ b2,
    const float* __restrict__ x, float* __restrict__ out)
{
    __shared__ __align__(16) char smem[32768];

    const int tid = threadIdx.x;
    const int l   = tid & 63;
    const int wn  = tid >> 6;          // 0..7: cols wn*32..+32
    const int lr  = l & 15;
    const int q   = l >> 4;            // 0..3
    const int R0  = blockIdx.x * 32;

    // ---- DWT phase: fill ll_pack (fragment order) ----
    {
        const int rr = tid >> 4;               // 0..31 row
        const int w0 = tid & 15;
        const int gbf = R0 + rr;
        const float* xr = x + ((size_t)(gbf >> 7) * F_DIM + (size_t)(gbf & 127) * 2) * C_DIM;
        const float* xs = xr + C_DIM;
#pragma unroll
        for (int half = 0; half < 2; ++half) {
            const int w = w0 + half * 16;      // 16B slot in row: c2 = w*8..+7
            float4 ra[4], rb[4];
#pragma unroll
            for (int i = 0; i < 4; ++i) {
                ra[i] = ((const float4*)xr)[w * 4 + i];
                rb[i] = ((const float4*)xs)[w * 4 + i];
            }
            const float* pa = (const float*)ra;
            const float* pb = (const float*)rb;
            bf16x8 pk;
#pragma unroll
            for (int e = 0; e < 8; ++e)
                pk[e] = (bf16)(0.5f * (pa[2*e] + pa[2*e+1] + pb[2*e] + pb[2*e+1]));
            int slot = (((rr >> 4) * 8 + (w >> 2)) * 64) + ((w & 3) << 4) + (rr & 15);
            *(bf16x8*)(smem + slot * 16) = pk;
        }
    }
    __syncthreads();

    f32x4 acc2[2][2];
#pragma unroll
    for (int m = 0; m < 2; ++m)
#pragma unroll
        for (int n = 0; n < 2; ++n)
            acc2[m][n] = (f32x4){0.f, 0.f, 0.f, 0.f};

    for (int hc = 0; hc < 8; ++hc) {
        // ---- prefetch ALL GEMM1 weight frags of this chunk (16 loads in flight) ----
        bf16x8 bw1[2][8];
#pragma unroll
        for (int n = 0; n < 2; ++n) {
            const int hblk = hc * 16 + wn * 2 + n;
#pragma unroll
            for (int t = 0; t < 8; ++t)
                bw1[n][t] = *(const bf16x8*)(w1pp + (((size_t)hblk * 8 + t) * 64 + l) * 8);
        }

        // ---- GEMM1: S1[32][32 cols of this wave] over K=256 ----
        f32x4 acc1[2][2];
#pragma unroll
        for (int m = 0; m < 2; ++m)
#pragma unroll
            for (int n = 0; n < 2; ++n)
                acc1[m][n] = (f32x4){0.f, 0.f, 0.f, 0.f};

#pragma unroll
        for (int t = 0; t < 8; ++t) {
            bf16x8 af[2];
#pragma unroll
            for (int m = 0; m < 2; ++m)
                af[m] = *(const bf16x8*)(smem + ((m * 8 + t) * 64 + l) * 16);
#pragma unroll
            for (int n = 0; n < 2; ++n)
#pragma unroll
                for (int m = 0; m < 2; ++m)
                    acc1[m][n] = __builtin_amdgcn_mfma_f32_16x16x32_bf16(af[m], bw1[n][t], acc1[m][n], 0, 0, 0);
        }

        // ---- GELU -> Hs_pack ----
#pragma unroll
        for (int n = 0; n < 2; ++n) {
            const int col = wn * 32 + n * 16 + lr;       // hid within chunk
            const float bs = b1[hc * 256 + col];
            const int t2 = col >> 5, qq = (col >> 3) & 3, e = col & 7;
#pragma unroll
            for (int m = 0; m < 2; ++m) {
#pragma unroll
                for (int j = 0; j < 4; ++j) {
                    float v = acc1[m][n][j] + bs;
                    float tt = v * (0.79788456080f + 0.03567740814f * v * v);
                    float ex = __expf(-2.0f * tt);
                    float g = v / (1.0f + ex);           // v * sigmoid(2t)
                    const int row = m * 16 + q * 4 + j;
                    int off = ((m * 8 + t2) * 64 + (qq << 4) + (row & 15)) * 8 + e;
                    *(bf16*)(smem + 16384 + off * 2) = (bf16)g;
                }
            }
        }

        // ---- prefetch ALL GEMM2 weight frags (lands under barrier + ds_reads) ----
        bf16x8 bw2[2][8];
#pragma unroll
        for (int n = 0; n < 2; ++n) {
            const int c2blk = wn * 2 + n;
#pragma unroll
            for (int t = 0; t < 8; ++t)
                bw2[n][t] = *(const bf16x8*)(w2pp + (((size_t)c2blk * 64 + hc * 8 + t) * 64 + l) * 8);
        }
        __syncthreads();   // Hs complete, visible to all waves

        // ---- GEMM2: acc2 += Hs @ W2chunk^T ----
#pragma unroll
        for (int t = 0; t < 8; ++t) {
            bf16x8 af[2];
#pragma unroll
            for (int m = 0; m < 2; ++m)
                af[m] = *(const bf16x8*)(smem + 16384 + ((m * 8 + t) * 64 + l) * 16);
#pragma unroll
            for (int n = 0; n < 2; ++n)
#pragma unroll
                for (int m = 0; m < 2; ++m)
                    acc2[m][n] = __builtin_amdgcn_mfma_f32_16x16x32_bf16(af[m], bw2[n][t], acc2[m][n], 0, 0, 0);
        }
        __syncthreads();   // all waves done reading Hs before next GELU overwrites
    }

    // ---- epilogue: bias + iDWT (recompute lh/hl/hh from x) -> out ----
#pragma unroll
    for (int n = 0; n < 2; ++n) {
        const int c2 = wn * 32 + n * 16 + lr;
        const float bs = b2[c2];
#pragma unroll
        for (int m = 0; m < 2; ++m) {
#pragma unroll
            for (int j = 0; j < 4; ++j) {
                const int gbf = R0 + m * 16 + q * 4 + j;
                const int b = gbf >> 7, f2 = gbf & 127;
                const float* xr = x + ((size_t)b * F_DIM + (size_t)f2 * 2) * C_DIM;
                float2 p0 = ((const float2*)xr)[c2];
                float2 p1 = ((const float2*)(xr + C_DIM))[c2];
                float a = p0.x, bb = p0.y, cc = p1.x, dd = p1.y;
                float llv = acc2[m][n][j] + bs;
                float lh = 0.5f * (a + bb - cc - dd);
                float hl = 0.5f * (a - bb + cc - dd);
                float hh = 0.5f * (a - bb - cc + dd);
                float2 o0, o1;
                o0.x = 0.5f * (llv + lh + hl + hh);
                o0.y = 0.5f * (llv + lh - hl - hh);
                o1.x = 0.5f * (llv - lh + hl - hh);
                o1.y = 0.5f * (llv - lh - hl + hh);
                float* orow = out + ((size_t)b * F_DIM + (size_t)f2 * 2) * C_DIM;
                ((float2*)orow)[c2] = o0;
                ((float2*)(orow + C_DIM))[c2] = o1;
            }
        }
    }
}

extern "C" void kernel_launch(void* const* d_in, const int* in_sizes, int n_in,
                              void* d_out, int out_size, void* d_ws, size_t ws_size,
                              hipStream_t stream) {
    const float* x     = (const float*)d_in[0];
    const float* fc1_w = (const float*)d_in[1];
    const float* fc1_b = (const float*)d_in[2];
    const float* fc2_w = (const float*)d_in[3];
    const float* fc2_b = (const float*)d_in[4];
    float* out = (float*)d_out;

    char* ws = (char*)d_ws;
    bf16* w1pp = (bf16*)(ws + OFF_W1P);
    bf16* w2pp = (bf16*)(ws + OFF_W2);

    prep_kernel<<<4096, 256, 0, stream>>>(fc1_w, fc2_w, w1pp, w2pp);
    fused_mlp<<<MROWS / 32, 512, 0, stream>>>(w1pp, w2pp, fc1_b, fc2_b, x, out);
}